// Round 16
// baseline (435.680 us; speedup 1.0000x reference)
//
#include <hip/hip_runtime.h>
#include <stdint.h>

#define BB 4
#define SS 2048
#define DMODEL 1024
#define NH 16
#define FF 4096
#define MROWS (BB*SS)   // 8192

typedef __bf16 bf16x8 __attribute__((ext_vector_type(8)));
typedef __bf16 bf16x2t __attribute__((ext_vector_type(2)));
typedef float f32x4 __attribute__((ext_vector_type(4)));
typedef float f32x16 __attribute__((ext_vector_type(16)));
typedef unsigned uintx4 __attribute__((ext_vector_type(4)));

__device__ __forceinline__ unsigned short f2b(float f) {
  unsigned u = __float_as_uint(f);
  unsigned r = (u + 0x7FFFu + ((u >> 16) & 1u)) >> 16;
  return (unsigned short)r;
}
__device__ __forceinline__ float b2f(unsigned short u) {
  return __uint_as_float((unsigned)u << 16);
}

__device__ __forceinline__ unsigned pack2bf(float a, float b) {
  bf16x2t v = {(__bf16)a, (__bf16)b};
  return __builtin_bit_cast(unsigned, v);
}

__device__ __forceinline__ void pls32(unsigned& x, unsigned& y) {
#if defined(__has_builtin) && __has_builtin(__builtin_amdgcn_permlane32_swap)
  auto r = __builtin_amdgcn_permlane32_swap(x, y, 0, 0);
  x = (unsigned)r[0];
  y = (unsigned)r[1];
#else
  const unsigned sx = (unsigned)__shfl_xor((int)x, 32, 64);
  const unsigned sy = (unsigned)__shfl_xor((int)y, 32, 64);
  const bool hi = ((threadIdx.x >> 5) & 1) != 0;
  const unsigned nx = hi ? sy : x;
  const unsigned ny = hi ? y : sx;
  x = nx; y = ny;
#endif
}

// async global->LDS, 16B per lane; LDS dest = wave-uniform base + lane*16
__device__ __forceinline__ void gload_lds16(const void* g, void* l) {
  __builtin_amdgcn_global_load_lds(
      (const __attribute__((address_space(1))) void*)g,
      (__attribute__((address_space(3))) void*)l, 16, 0, 0);
}

// XOR-swizzled fragment read from a [rows][64] bf16 LDS tile (GEMM)
__device__ __forceinline__ bf16x8 lds_frag(const unsigned short* base, int row, int k) {
  unsigned off = (unsigned)((row * 128 + k * 2) ^ ((row & 7) << 4));
  return *reinterpret_cast<const bf16x8*>(reinterpret_cast<const char*>(base) + off);
}

// rotation-swizzled fragment read from a [rows][64] bf16 LDS tile (attn)
__device__ __forceinline__ bf16x8 frag_rot(const unsigned short* base, int row, int kElem) {
  const int cb = kElem * 2;
  const unsigned off = (unsigned)(row * 128 + ((((cb >> 4) + row) & 7) << 4) + (cb & 15));
  return *reinterpret_cast<const bf16x8*>(reinterpret_cast<const char*>(base) + off);
}

// ---------------- converts ----------------
__global__ __launch_bounds__(256) void f32_to_bf16_k(const float* __restrict__ in,
                                                     unsigned short* __restrict__ out, int n8) {
  const int i = blockIdx.x * 256 + threadIdx.x;
  if (i >= n8) return;
  const float4* p = reinterpret_cast<const float4*>(in) + (size_t)i * 2;
  const float4 a = p[0], c = p[1];
  uint4 o;
  o.x = (unsigned)f2b(a.x) | ((unsigned)f2b(a.y) << 16);
  o.y = (unsigned)f2b(a.z) | ((unsigned)f2b(a.w) << 16);
  o.z = (unsigned)f2b(c.x) | ((unsigned)f2b(c.y) << 16);
  o.w = (unsigned)f2b(c.z) | ((unsigned)f2b(c.w) << 16);
  reinterpret_cast<uint4*>(out)[i] = o;
}

// batched 4x: (1024,1024) f32 -> (1024,1024)^T bf16, z selects the weight
__global__ __launch_bounds__(256) void transpose_convert4_k(
    const float* __restrict__ i0, const float* __restrict__ i1,
    const float* __restrict__ i2, const float* __restrict__ i3,
    unsigned short* __restrict__ o0, unsigned short* __restrict__ o1,
    unsigned short* __restrict__ o2, unsigned short* __restrict__ o3) {
  __shared__ float tile[32][33];
  const int z = blockIdx.z;
  const float* in = (z == 0) ? i0 : (z == 1) ? i1 : (z == 2) ? i2 : i3;
  unsigned short* out = (z == 0) ? o0 : (z == 1) ? o1 : (z == 2) ? o2 : o3;
  const int c0 = blockIdx.x * 32, r0 = blockIdx.y * 32;
  const int tx = threadIdx.x, ty = threadIdx.y;
  #pragma unroll
  for (int i = 0; i < 4; ++i)
    tile[ty + i * 8][tx] = in[(size_t)(r0 + ty + i * 8) * 1024 + c0 + tx];
  __syncthreads();
  #pragma unroll
  for (int i = 0; i < 4; ++i)
    out[(size_t)(c0 + ty + i * 8) * 1024 + r0 + tx] = f2b(tile[tx][ty + i * 8]);
}

__global__ __launch_bounds__(256) void transpose_convert_k(const float* __restrict__ in,
                                                           unsigned short* __restrict__ out,
                                                           int R, int C) {
  __shared__ float tile[32][33];
  const int c0 = blockIdx.x * 32, r0 = blockIdx.y * 32;
  const int tx = threadIdx.x, ty = threadIdx.y;
  #pragma unroll
  for (int i = 0; i < 4; ++i)
    tile[ty + i * 8][tx] = in[(size_t)(r0 + ty + i * 8) * C + c0 + tx];
  __syncthreads();
  #pragma unroll
  for (int i = 0; i < 4; ++i)
    out[(size_t)(c0 + ty + i * 8) * R + r0 + tx] = f2b(tile[tx][ty + i * 8]);
}

__global__ __launch_bounds__(256) void v_transpose_k(const unsigned short* __restrict__ Vb,
                                                     unsigned short* __restrict__ Vt) {
  __shared__ unsigned short tile[32][33];
  const int bh = blockIdx.z, b = bh >> 4, h = bh & 15;
  const int s0 = blockIdx.x * 32, d0 = blockIdx.y * 32;
  const int tx = threadIdx.x, ty = threadIdx.y;
  #pragma unroll
  for (int i = 0; i < 4; ++i)
    tile[ty + i * 8][tx] = Vb[(size_t)(b * SS + s0 + ty + i * 8) * DMODEL + h * 64 + d0 + tx];
  __syncthreads();
  #pragma unroll
  for (int i = 0; i < 4; ++i)
    Vt[(size_t)(bh * 64 + d0 + ty + i * 8) * SS + s0 + tx] = tile[tx][ty + i * 8];
}

__global__ __launch_bounds__(256) void mask_pack_k(const unsigned char* __restrict__ mask,
                                                   unsigned long long* __restrict__ mbits, int total) {
  const int idx = blockIdx.x * 256 + threadIdx.x;
  if (idx >= total) return;
  const uint4* p = reinterpret_cast<const uint4*>(mask) + (size_t)idx * 4;
  unsigned long long bits = 0ull;
  #pragma unroll
  for (int q = 0; q < 4; ++q) {
    uint4 v = p[q];
    unsigned wds[4] = {v.x, v.y, v.z, v.w};
    #pragma unroll
    for (int j = 0; j < 4; ++j)
      #pragma unroll
      for (int by = 0; by < 4; ++by)
        if ((wds[j] >> (by * 8)) & 0xFFu) bits |= 1ull << (q * 16 + j * 4 + by);
  }
  mbits[idx] = bits;
}

// ---------------- GEMM: 128x128, counted-vmcnt 2-stage + 8x8 supertile order ----------------
#define CQ 0.18033688011112042f   // log2(e)/8
template <int EPI>
__global__ __launch_bounds__(256, 3) void gemm2_k(const unsigned short* __restrict__ A,
                                                  const unsigned short* __restrict__ Bt,
                                                  const float* __restrict__ bias_a,
                                                  const float* __restrict__ bias_b,
                                                  const float* __restrict__ bias_c,
                                                  void* __restrict__ Cout, int N, int K) {
  __shared__ __align__(16) unsigned short As[2][128 * 64];
  __shared__ __align__(16) unsigned short Bs[2][128 * 64];
  const int t = threadIdx.x;
  const int lane = t & 63, w = t >> 6;
  const int wr = w >> 1, wc = w & 1;
  const int lr = lane & 15, lg = lane >> 4;

  const int nwg = gridDim.x;
  const int q8 = nwg >> 3;
  const int wg = (blockIdx.x & 7) * q8 + (blockIdx.x >> 3);
  const int sid = wg >> 6, within = wg & 63;
  const int smb = sid & 7, snb = sid >> 3;
  const int mb = smb * 8 + (within & 7);
  const int nb = snb * 8 + (within >> 3);
  const int m0 = mb * 128, n0 = nb * 128;

  const int srow = t >> 3;
  const unsigned cxor = (unsigned)(((t & 7) * 16) ^ (((t >> 3) & 7) << 4));
  const char* Asrc = reinterpret_cast<const char*>(A) + ((size_t)(m0 + srow) * K) * 2 + cxor;
  const char* Bsrc = reinterpret_cast<const char*>(Bt) + ((size_t)(n0 + srow) * K) * 2 + cxor;
  const size_t rstep = (size_t)32 * K * 2;
  char* AsB[2] = {reinterpret_cast<char*>(As[0]) + w * 1024, reinterpret_cast<char*>(As[1]) + w * 1024};
  char* BsB[2] = {reinterpret_cast<char*>(Bs[0]) + w * 1024, reinterpret_cast<char*>(Bs[1]) + w * 1024};

  auto stage = [&](int buf, int kt) {
    const char* ak = Asrc + (size_t)kt * 128;
    const char* bk = Bsrc + (size_t)kt * 128;
    #pragma unroll
    for (int c = 0; c < 4; ++c) {
      gload_lds16(ak + c * rstep, AsB[buf] + c * 4096);
      gload_lds16(bk + c * rstep, BsB[buf] + c * 4096);
    }
  };

  f32x4 acc[4][4] = {};
  const int nt = K >> 6;

  stage(0, 0);
  stage(1, 1);
  asm volatile("s_waitcnt vmcnt(8)" ::: "memory");
  __builtin_amdgcn_s_barrier();

  int cur = 0;
  for (int kt = 0; kt < nt; ++kt) {
    bf16x8 af[2][4], bfr[2][4];
    #pragma unroll
    for (int kk = 0; kk < 2; ++kk) {
      #pragma unroll
      for (int m = 0; m < 4; ++m)
        af[kk][m] = lds_frag(As[cur], wr * 64 + m * 16 + lr, kk * 32 + lg * 8);
      #pragma unroll
      for (int n = 0; n < 4; ++n)
        bfr[kk][n] = lds_frag(Bs[cur], wc * 64 + n * 16 + lr, kk * 32 + lg * 8);
    }
    __builtin_amdgcn_s_setprio(1);
    #pragma unroll
    for (int m = 0; m < 4; ++m)
      #pragma unroll
      for (int n = 0; n < 4; ++n)
        acc[m][n] = __builtin_amdgcn_mfma_f32_16x16x32_bf16(af[0][m], bfr[0][n], acc[m][n], 0, 0, 0);
    __builtin_amdgcn_s_setprio(0);

    asm volatile("s_waitcnt lgkmcnt(0)" ::: "memory");
    __builtin_amdgcn_s_barrier();
    if (kt + 2 < nt) {
      stage(cur, kt + 2);
      asm volatile("s_waitcnt vmcnt(8)" ::: "memory");
    } else {
      asm volatile("s_waitcnt vmcnt(0)" ::: "memory");
    }
    __builtin_amdgcn_s_barrier();

    __builtin_amdgcn_s_setprio(1);
    #pragma unroll
    for (int m = 0; m < 4; ++m)
      #pragma unroll
      for (int n = 0; n < 4; ++n)
        acc[m][n] = __builtin_amdgcn_mfma_f32_16x16x32_bf16(af[1][m], bfr[1][n], acc[m][n], 0, 0, 0);
    __builtin_amdgcn_s_setprio(0);
    cur ^= 1;
  }

  const int ccol0 = wc * 64;
  if constexpr (EPI == 3) {
    const int g3 = n0 >> 10;  // 0=Q,1=K,2=V
    const float* bias = (g3 == 0) ? bias_a : (g3 == 1) ? bias_b : bias_c;
    const float scl = (g3 == 0) ? CQ : 1.0f;
    unsigned short* Og = reinterpret_cast<unsigned short*>(Cout) + (size_t)g3 * MROWS * DMODEL;
    const int ncol0 = (n0 & 1023) + ccol0;
    float bv[4];
    #pragma unroll
    for (int n = 0; n < 4; ++n) bv[n] = bias[ncol0 + n * 16 + lr];
    #pragma unroll
    for (int m = 0; m < 4; ++m)
      #pragma unroll
      for (int n = 0; n < 4; ++n)
        #pragma unroll
        for (int i = 0; i < 4; ++i) {
          const float v = (acc[m][n][i] + bv[n]) * scl;
          const size_t row = (size_t)(m0 + wr * 64 + m * 16 + lg * 4 + i);
          Og[row * DMODEL + (ncol0 + n * 16 + lr)] = f2b(v);
        }
  } else {
    float bv[4];
    #pragma unroll
    for (int n = 0; n < 4; ++n) bv[n] = bias_a[n0 + ccol0 + n * 16 + lr];
    #pragma unroll
    for (int m = 0; m < 4; ++m)
      #pragma unroll
      for (int n = 0; n < 4; ++n)
        #pragma unroll
        for (int i = 0; i < 4; ++i) {
          float v = acc[m][n][i] + bv[n];
          if (EPI == 1) v = fmaxf(v, 0.0f);
          const size_t row = (size_t)(m0 + wr * 64 + m * 16 + lg * 4 + i);
          const size_t col = (size_t)(n0 + ccol0 + n * 16 + lr);
          reinterpret_cast<unsigned short*>(Cout)[row * N + col] = f2b(v);
        }
  }
}

// ---------------- flash attention v9b: attn9 + launch_bounds(256,4) ----------------
// Round-14's best attn structure; the ONLY change is the register cap 170->128
// (=512/4 unified regs) to fit a 4th wave/SIMD. Live-set arithmetic: qf 16 +
// ao 32 + st 16 + pack 8 + addressing ~12 + misc ~20 = ~105-115 < 128.
__global__ __launch_bounds__(256, 4) void attn9_k(const unsigned short* __restrict__ Qb,
                                                  const unsigned short* __restrict__ Kb,
                                                  const unsigned short* __restrict__ Vt,
                                                  const unsigned long long* __restrict__ mbits,
                                                  unsigned short* __restrict__ ctx) {
  __shared__ __align__(16) unsigned short smem[16384];
  unsigned short* KsC = smem;
  unsigned short* KsN = smem + 4096;
  unsigned short* VsC = smem + 8192;
  unsigned short* VsN = smem + 12288;

  const int t = threadIdx.x;
  const int lane = t & 63, w = t >> 6;
  const int lo = lane & 31, hi = lane >> 5;

  const int flat = blockIdx.x;
  const int bid = (flat & 7) * 128 + (flat >> 3);   // bijective XCD swizzle (1024 wg)
  const int bh = bid >> 4, qb = bid & 15;
  const int b = bh >> 4, h = bh & 15;
  const int q0 = qb * 128 + w * 32;

  bf16x8 qf[4];
  {
    const unsigned short* qp = Qb + (size_t)(b * SS + q0 + lo) * DMODEL + h * 64 + hi * 8;
    #pragma unroll
    for (int ds = 0; ds < 4; ++ds) qf[ds] = *reinterpret_cast<const bf16x8*>(qp + ds * 16);
  }

  f32x16 ao0 = {}, ao1 = {};
  float lsum = 0.0f;

  const int srow = t >> 3;
  const int gsw = ((t & 7) - srow) & 7;
  const char* Ksrc = reinterpret_cast<const char*>(Kb) +
                     ((size_t)(b * SS + srow) * DMODEL + h * 64 + gsw * 8) * 2;
  const char* Vsrc = reinterpret_cast<const char*>(Vt) +
                     ((size_t)(bh * 64 + srow) * SS + gsw * 8) * 2;
  const unsigned wdo = (unsigned)(w * 1024);

  auto stage = [&](int kv, unsigned short* Kbuf, unsigned short* Vbuf) {
    const char* ks0 = Ksrc + (size_t)kv * (64 * DMODEL * 2);
    const char* vs0 = Vsrc + (size_t)kv * 128;
    char* kd = reinterpret_cast<char*>(Kbuf) + wdo;
    char* vd = reinterpret_cast<char*>(Vbuf) + wdo;
    gload_lds16(ks0, kd);
    gload_lds16(ks0 + (size_t)32 * DMODEL * 2, kd + 4096);
    gload_lds16(vs0, vd);
    gload_lds16(vs0 + (size_t)32 * SS * 2, vd + 4096);
  };

  const unsigned long long* mrow = mbits + (size_t)(b * SS + q0 + lo) * (SS / 64);

  stage(0, KsC, VsC);
  asm volatile("s_waitcnt vmcnt(0)" ::: "memory");
  __syncthreads();

  for (int kv = 0; kv < SS / 64; ++kv) {
    if (kv + 1 < SS / 64) stage(kv + 1, KsN, VsN);

    const unsigned long long mb = mrow[kv];
    float ls = 0.0f;

    #pragma unroll
    for (int half = 0; half < 2; ++half) {
      // QK^T for this half's 32 keys
      f32x16 st = {};
      __builtin_amdgcn_s_setprio(1);
      #pragma unroll
      for (int ds = 0; ds < 4; ++ds) {
        const int kcol = ds * 16 + hi * 8;
        st = __builtin_amdgcn_mfma_f32_32x32x16_bf16(
            frag_rot(KsC, half * 32 + lo, kcol), qf[ds], st, 0, 0, 0);
      }
      __builtin_amdgcn_s_setprio(0);

      if (__any(mb != 0ull)) {
        #pragma unroll
        for (int r = 0; r < 16; ++r) {
          const int k = (r & 3) + 8 * (r >> 2) + 4 * hi + 32 * half;
          if ((mb >> k) & 1ull) st[r] = -20.0f;
        }
      }

      // exp + tree-sum (no-max softmax; Q pre-scaled by log2(e)/8)
      #pragma unroll
      for (int r = 0; r < 16; ++r) st[r] = exp2f(st[r]);
      {
        float ps[8];
        #pragma unroll
        for (int r = 0; r < 8; ++r) ps[r] = st[r] + st[r + 8];
        #pragma unroll
        for (int r = 0; r < 4; ++r) ps[r] += ps[r + 4];
        ls += (ps[0] + ps[1]) + (ps[2] + ps[3]);
      }

      // pack half -> 8 words (T12)
      unsigned c0 = pack2bf(st[0], st[1]);
      unsigned c1 = pack2bf(st[2], st[3]);
      unsigned c2 = pack2bf(st[4], st[5]);
      unsigned c3 = pack2bf(st[6], st[7]);
      unsigned c4 = pack2bf(st[8], st[9]);
      unsigned c5 = pack2bf(st[10], st[11]);
      unsigned c6 = pack2bf(st[12], st[13]);
      unsigned c7 = pack2bf(st[14], st[15]);
      pls32(c0, c2); pls32(c1, c3); pls32(c4, c6); pls32(c5, c7);

      // PV for this half's two k-slices
      const uintx4 pv0 = {c0, c1, c2, c3};
      const uintx4 pv1 = {c4, c5, c6, c7};
      const bf16x8 pb0 = __builtin_bit_cast(bf16x8, pv0);
      const bf16x8 pb1 = __builtin_bit_cast(bf16x8, pv1);
      const int s0c = (half * 2 + 0) * 16 + hi * 8;
      const int s1c = (half * 2 + 1) * 16 + hi * 8;
      __builtin_amdgcn_s_setprio(1);
      ao0 = __builtin_amdgcn_mfma_f32_32x32x16_bf16(frag_rot(VsC, lo, s0c), pb0, ao0, 0, 0, 0);
      ao1 = __builtin_amdgcn_mfma_f32_32x32x16_bf16(frag_rot(VsC, 32 + lo, s0c), pb0, ao1, 0, 0, 0);
      ao0 = __builtin_amdgcn_mfma_f32_32x32x16_bf16(frag_rot(VsC, lo, s1c), pb1, ao0, 0, 0, 0);
      ao1 = __builtin_amdgcn_mfma_f32_32x32x16_bf16(frag_rot(VsC, 32 + lo, s1c), pb1, ao1, 0, 0, 0);
      __builtin_amdgcn_s_setprio(0);
    }

    ls += __shfl_xor(ls, 32, 64);
    lsum += ls;

    asm volatile("s_waitcnt vmcnt(0)" ::: "memory");
    __syncthreads();
    unsigned short* tk = KsC; KsC = KsN; KsN = tk;
    unsigned short* tv = VsC; VsC = VsN; VsN = tv;
  }

  const float inv = 1.0f / lsum;
  unsigned short* Ob = smem + w * 2048;
  #pragma unroll
  for (int dt = 0; dt < 2; ++dt) {
    #pragma unroll
    for (int r = 0; r < 16; ++r) {
      const int d = dt * 32 + (r & 3) + 8 * (r >> 2) + 4 * hi;
      const float v = (dt ? ao1[r] : ao0[r]) * inv;
      const unsigned off = (unsigned)((lo * 128 + d * 2) ^ ((lo & 7) << 4));
      *reinterpret_cast<unsigned short*>(reinterpret_cast<char*>(Ob) + off) = f2b(v);
    }
  }
  __syncthreads();
  const int rr = lane >> 1, xh = (lane & 1) * 64;
  char* crow_g = reinterpret_cast<char*>(ctx) +
                 ((size_t)(b * SS + q0 + rr) * DMODEL + h * 64) * 2;
  #pragma unroll
  for (int c = 0; c < 4; ++c) {
    const unsigned off = (unsigned)((rr * 128 + xh + c * 16) ^ ((rr & 7) << 4));
    const uint4 vv = *reinterpret_cast<const uint4*>(reinterpret_cast<const char*>(Ob) + off);
    *reinterpret_cast<uint4*>(crow_g + xh + c * 16) = vv;
  }
}

// ---------------- LayerNorm variants (bf16 activations, f32 math) ----------------
__global__ __launch_bounds__(256) void ln1_k(const unsigned short* __restrict__ a,
                                             const unsigned short* __restrict__ res,
                                             const float* __restrict__ g,
                                             const float* __restrict__ be,
                                             unsigned short* __restrict__ ob) {
  const int row = blockIdx.x, t = threadIdx.x;
  const ushort4 av = reinterpret_cast<const ushort4*>(a + (size_t)row * DMODEL)[t];
  const ushort4 rv = reinterpret_cast<const ushort4*>(res + (size_t)row * DMODEL)[t];
  float v0 = b2f(av.x) + b2f(rv.x), v1 = b2f(av.y) + b2f(rv.y);
  float v2 = b2f(av.z) + b2f(rv.z), v3 = b2f(av.w) + b2f(rv.w);
  float s = v0 + v1 + v2 + v3;
  float ss = v0 * v0 + v1 * v1 + v2 * v2 + v3 * v3;
  #pragma unroll
  for (int off = 1; off < 64; off <<= 1) {
    s += __shfl_xor(s, off, 64);
    ss += __shfl_xor(ss, off, 64);
  }
  __shared__ float red[8];
  const int wv = t >> 6;
  if ((t & 63) == 0) { red[wv] = s; red[4 + wv] = ss; }
  __syncthreads();
  s = red[0] + red[1] + red[2] + red[3];
  ss = red[4] + red[5] + red[6] + red[7];
  const float mu = s * (1.0f / DMODEL);
  const float rs = rsqrtf(ss * (1.0f / DMODEL) - mu * mu + 1e-6f);
  const float4 gg = reinterpret_cast<const float4*>(g)[t];
  const float4 bb = reinterpret_cast<const float4*>(be)[t];
  ushort4 u;
  u.x = f2b((v0 - mu) * rs * gg.x + bb.x);
  u.y = f2b((v1 - mu) * rs * gg.y + bb.y);
  u.z = f2b((v2 - mu) * rs * gg.z + bb.z);
  u.w = f2b((v3 - mu) * rs * gg.w + bb.w);
  reinterpret_cast<ushort4*>(ob + (size_t)row * DMODEL)[t] = u;
}

__global__ __launch_bounds__(256) void ln2_k(const unsigned short* __restrict__ a,
                                             const unsigned short* __restrict__ res,
                                             const float* __restrict__ g,
                                             const float* __restrict__ be,
                                             float* __restrict__ of) {
  const int row = blockIdx.x, t = threadIdx.x;
  const ushort4 av = reinterpret_cast<const ushort4*>(a + (size_t)row * DMODEL)[t];
  const ushort4 rv = reinterpret_cast<const ushort4*>(res + (size_t)row * DMODEL)[t];
  float v0 = b2f(av.x) + b2f(rv.x), v1 = b2f(av.y) + b2f(rv.y);
  float v2 = b2f(av.z) + b2f(rv.z), v3 = b2f(av.w) + b2f(rv.w);
  float s = v0 + v1 + v2 + v3;
  float ss = v0 * v0 + v1 * v1 + v2 * v2 + v3 * v3;
  #pragma unroll
  for (int off = 1; off < 64; off <<= 1) {
    s += __shfl_xor(s, off, 64);
    ss += __shfl_xor(ss, off, 64);
  }
  __shared__ float red[8];
  const int wv = t >> 6;
  if ((t & 63) == 0) { red[wv] = s; red[4 + wv] = ss; }
  __syncthreads();
  s = red[0] + red[1] + red[2] + red[3];
  ss = red[4] + red[5] + red[6] + red[7];
  const float mu = s * (1.0f / DMODEL);
  const float rs = rsqrtf(ss * (1.0f / DMODEL) - mu * mu + 1e-6f);
  const float4 gg = reinterpret_cast<const float4*>(g)[t];
  const float4 bb = reinterpret_cast<const float4*>(be)[t];
  float4 o;
  o.x = (v0 - mu) * rs * gg.x + bb.x;
  o.y = (v1 - mu) * rs * gg.y + bb.y;
  o.z = (v2 - mu) * rs * gg.z + bb.z;
  o.w = (v3 - mu) * rs * gg.w + bb.w;
  reinterpret_cast<float4*>(of + (size_t)row * DMODEL)[t] = o;
}

extern "C" void kernel_launch(void* const* d_in, const int* in_sizes, int n_in,
                              void* d_out, int out_size, void* d_ws, size_t ws_size,
                              hipStream_t stream) {
  const float* src = (const float*)d_in[0];
  const unsigned char* mask = (const unsigned char*)d_in[1];
  const float* Wq = (const float*)d_in[2];
  const float* bq = (const float*)d_in[3];
  const float* Wk = (const float*)d_in[4];
  const float* bk = (const float*)d_in[5];
  const float* Wv = (const float*)d_in[6];
  const float* bv = (const float*)d_in[7];
  const float* Wo = (const float*)d_in[8];
  const float* bo = (const float*)d_in[9];
  const float* ln1_g = (const float*)d_in[10];
  const float* ln1_b = (const float*)d_in[11];
  const float* W1 = (const float*)d_in[12];
  const float* b1 = (const float*)d_in[13];
  const float* W2 = (const float*)d_in[14];
  const float* b2 = (const float*)d_in[15];
  const float* ln2_g = (const float*)d_in[16];
  const float* ln2_b = (const float*)d_in[17];

  char* ws = (char*)d_ws;
  size_t off = 0;
  auto alloc = [&](size_t bytes) {
    char* p = ws + off;
    off += (bytes + 255) & ~(size_t)255;
    return p;
  };
  unsigned short* srcb = (unsigned short*)alloc((size_t)MROWS * DMODEL * 2);
  unsigned short* WqT  = (unsigned short*)alloc((size_t)DMODEL * DMODEL * 2);
  unsigned short* WkT  = (unsigned short*)alloc((size_t)DMODEL * DMODEL * 2);
  unsigned short* WvT  = (unsigned short*)alloc((size_t)DMODEL * DMODEL * 2);
  unsigned short* WoT  = (unsigned short*)alloc((size_t)DMODEL * DMODEL * 2);
  unsigned short* W1T  = (unsigned short*)alloc((size_t)FF * DMODEL * 2);
  unsigned short* W2T  = (unsigned short*)alloc((size_t)DMODEL * FF * 2);
  unsigned short* Qb   = (unsigned short*)alloc((size_t)MROWS * DMODEL * 2);
  unsigned short* Kb   = (unsigned short*)alloc((size_t)MROWS * DMODEL * 2);
  unsigned short* Vb   = (unsigned short*)alloc((size_t)MROWS * DMODEL * 2);
  unsigned short* Vt   = (unsigned short*)alloc((size_t)MROWS * DMODEL * 2);
  unsigned short* ctx  = (unsigned short*)alloc((size_t)MROWS * DMODEL * 2);
  unsigned short* aob  = (unsigned short*)alloc((size_t)MROWS * DMODEL * 2);  // Wo out (bf16)
  unsigned short* xb   = (unsigned short*)alloc((size_t)MROWS * DMODEL * 2);  // LN1 out (bf16)
  unsigned short* fob  = (unsigned short*)alloc((size_t)MROWS * DMODEL * 2);  // W2 out (bf16)
  unsigned short* hb   = (unsigned short*)alloc((size_t)MROWS * FF * 2);
  unsigned long long* mbits = (unsigned long long*)alloc((size_t)BB * SS * (SS / 64) * 8);
  float* outf = (float*)d_out;
  (void)Kb; (void)Vb;

  // converts
  f32_to_bf16_k<<<(MROWS * DMODEL / 8 + 255) / 256, 256, 0, stream>>>(src, srcb, MROWS * DMODEL / 8);
  dim3 tb(32, 8);
  transpose_convert4_k<<<dim3(32, 32, 4), tb, 0, stream>>>(Wq, Wk, Wv, Wo, WqT, WkT, WvT, WoT);
  transpose_convert_k<<<dim3(FF / 32, 32), tb, 0, stream>>>(W1, W1T, DMODEL, FF);
  transpose_convert_k<<<dim3(32, FF / 32), tb, 0, stream>>>(W2, W2T, FF, DMODEL);
  mask_pack_k<<<(BB * SS * (SS / 64) + 255) / 256, 256, 0, stream>>>(mask, mbits, BB * SS * (SS / 64));

  // fused QKV projection (N = 3072), 1536 blocks; Q pre-scaled by log2e/8
  gemm2_k<3><<<dim3(64 * 24), 256, 0, stream>>>(srcb, WqT, bq, bk, bv, Qb, 3072, DMODEL);

  v_transpose_k<<<dim3(SS / 32, 2, BB * NH), tb, 0, stream>>>(Vb, Vt);

  // low-register flash attention (4 waves/SIMD cap), 128 q/block, grid 1024
  attn9_k<<<dim3((SS / 128) * BB * NH), 256, 0, stream>>>(Qb, Kb, Vt, mbits, ctx);

  // output projection -> aob (bf16), 512 blocks
  gemm2_k<0><<<dim3(64 * 8), 256, 0, stream>>>(ctx, WoT, bo, nullptr, nullptr, aob, DMODEL, DMODEL);

  // x = LN1(srcb + att_out) -> xb (bf16)
  ln1_k<<<MROWS, 256, 0, stream>>>(aob, srcb, ln1_g, ln1_b, xb);

  // FFN: W1 (relu, 2048 blocks), W2 (512 blocks) -> fob (bf16)
  gemm2_k<1><<<dim3(64 * 32), 256, 0, stream>>>(xb, W1T, b1, nullptr, nullptr, hb, FF, DMODEL);
  gemm2_k<0><<<dim3(64 * 8), 256, 0, stream>>>(hb, W2T, b2, nullptr, nullptr, fob, DMODEL, FF);

  // out = LN2(ffn_out + x) -> d_out (f32)
  ln2_k<<<MROWS, 256, 0, stream>>>(fob, xb, ln2_g, ln2_b, outf);
}

// Round 17
// 415.181 us; speedup vs baseline: 1.0494x; 1.0494x over previous
//
#include <hip/hip_runtime.h>
#include <stdint.h>

#define BB 4
#define SS 2048
#define DMODEL 1024
#define NH 16
#define FF 4096
#define MROWS (BB*SS)   // 8192

typedef __bf16 bf16x8 __attribute__((ext_vector_type(8)));
typedef __bf16 bf16x2t __attribute__((ext_vector_type(2)));
typedef float f32x4 __attribute__((ext_vector_type(4)));
typedef float f32x16 __attribute__((ext_vector_type(16)));
typedef unsigned uintx4 __attribute__((ext_vector_type(4)));

__device__ __forceinline__ unsigned short f2b(float f) {
  unsigned u = __float_as_uint(f);
  unsigned r = (u + 0x7FFFu + ((u >> 16) & 1u)) >> 16;
  return (unsigned short)r;
}
__device__ __forceinline__ float b2f(unsigned short u) {
  return __uint_as_float((unsigned)u << 16);
}

__device__ __forceinline__ unsigned pack2bf(float a, float b) {
  bf16x2t v = {(__bf16)a, (__bf16)b};
  return __builtin_bit_cast(unsigned, v);
}

__device__ __forceinline__ void pls32(unsigned& x, unsigned& y) {
#if defined(__has_builtin) && __has_builtin(__builtin_amdgcn_permlane32_swap)
  auto r = __builtin_amdgcn_permlane32_swap(x, y, 0, 0);
  x = (unsigned)r[0];
  y = (unsigned)r[1];
#else
  const unsigned sx = (unsigned)__shfl_xor((int)x, 32, 64);
  const unsigned sy = (unsigned)__shfl_xor((int)y, 32, 64);
  const bool hi = ((threadIdx.x >> 5) & 1) != 0;
  const unsigned nx = hi ? sy : x;
  const unsigned ny = hi ? y : sx;
  x = nx; y = ny;
#endif
}

// async global->LDS, 16B per lane; LDS dest = wave-uniform base + lane*16
__device__ __forceinline__ void gload_lds16(const void* g, void* l) {
  __builtin_amdgcn_global_load_lds(
      (const __attribute__((address_space(1))) void*)g,
      (__attribute__((address_space(3))) void*)l, 16, 0, 0);
}

// XOR-swizzled fragment read from a [rows][64] bf16 LDS tile (GEMM)
__device__ __forceinline__ bf16x8 lds_frag(const unsigned short* base, int row, int k) {
  unsigned off = (unsigned)((row * 128 + k * 2) ^ ((row & 7) << 4));
  return *reinterpret_cast<const bf16x8*>(reinterpret_cast<const char*>(base) + off);
}

// rotation-swizzled fragment read from a [rows][64] bf16 LDS tile (attn)
__device__ __forceinline__ bf16x8 frag_rot(const unsigned short* base, int row, int kElem) {
  const int cb = kElem * 2;
  const unsigned off = (unsigned)(row * 128 + ((((cb >> 4) + row) & 7) << 4) + (cb & 15));
  return *reinterpret_cast<const bf16x8*>(reinterpret_cast<const char*>(base) + off);
}

// ---------------- converts ----------------
__global__ __launch_bounds__(256) void f32_to_bf16_k(const float* __restrict__ in,
                                                     unsigned short* __restrict__ out, int n8) {
  const int i = blockIdx.x * 256 + threadIdx.x;
  if (i >= n8) return;
  const float4* p = reinterpret_cast<const float4*>(in) + (size_t)i * 2;
  const float4 a = p[0], c = p[1];
  uint4 o;
  o.x = (unsigned)f2b(a.x) | ((unsigned)f2b(a.y) << 16);
  o.y = (unsigned)f2b(a.z) | ((unsigned)f2b(a.w) << 16);
  o.z = (unsigned)f2b(c.x) | ((unsigned)f2b(c.y) << 16);
  o.w = (unsigned)f2b(c.z) | ((unsigned)f2b(c.w) << 16);
  reinterpret_cast<uint4*>(out)[i] = o;
}

// batched 4x: (1024,1024) f32 -> (1024,1024)^T bf16, z selects the weight
__global__ __launch_bounds__(256) void transpose_convert4_k(
    const float* __restrict__ i0, const float* __restrict__ i1,
    const float* __restrict__ i2, const float* __restrict__ i3,
    unsigned short* __restrict__ o0, unsigned short* __restrict__ o1,
    unsigned short* __restrict__ o2, unsigned short* __restrict__ o3) {
  __shared__ float tile[32][33];
  const int z = blockIdx.z;
  const float* in = (z == 0) ? i0 : (z == 1) ? i1 : (z == 2) ? i2 : i3;
  unsigned short* out = (z == 0) ? o0 : (z == 1) ? o1 : (z == 2) ? o2 : o3;
  const int c0 = blockIdx.x * 32, r0 = blockIdx.y * 32;
  const int tx = threadIdx.x, ty = threadIdx.y;
  #pragma unroll
  for (int i = 0; i < 4; ++i)
    tile[ty + i * 8][tx] = in[(size_t)(r0 + ty + i * 8) * 1024 + c0 + tx];
  __syncthreads();
  #pragma unroll
  for (int i = 0; i < 4; ++i)
    out[(size_t)(c0 + ty + i * 8) * 1024 + r0 + tx] = f2b(tile[tx][ty + i * 8]);
}

__global__ __launch_bounds__(256) void transpose_convert_k(const float* __restrict__ in,
                                                           unsigned short* __restrict__ out,
                                                           int R, int C) {
  __shared__ float tile[32][33];
  const int c0 = blockIdx.x * 32, r0 = blockIdx.y * 32;
  const int tx = threadIdx.x, ty = threadIdx.y;
  #pragma unroll
  for (int i = 0; i < 4; ++i)
    tile[ty + i * 8][tx] = in[(size_t)(r0 + ty + i * 8) * C + c0 + tx];
  __syncthreads();
  #pragma unroll
  for (int i = 0; i < 4; ++i)
    out[(size_t)(c0 + ty + i * 8) * R + r0 + tx] = f2b(tile[tx][ty + i * 8]);
}

__global__ __launch_bounds__(256) void v_transpose_k(const unsigned short* __restrict__ Vb,
                                                     unsigned short* __restrict__ Vt) {
  __shared__ unsigned short tile[32][33];
  const int bh = blockIdx.z, b = bh >> 4, h = bh & 15;
  const int s0 = blockIdx.x * 32, d0 = blockIdx.y * 32;
  const int tx = threadIdx.x, ty = threadIdx.y;
  #pragma unroll
  for (int i = 0; i < 4; ++i)
    tile[ty + i * 8][tx] = Vb[(size_t)(b * SS + s0 + ty + i * 8) * DMODEL + h * 64 + d0 + tx];
  __syncthreads();
  #pragma unroll
  for (int i = 0; i < 4; ++i)
    Vt[(size_t)(bh * 64 + d0 + ty + i * 8) * SS + s0 + tx] = tile[tx][ty + i * 8];
}

__global__ __launch_bounds__(256) void mask_pack_k(const unsigned char* __restrict__ mask,
                                                   unsigned long long* __restrict__ mbits, int total) {
  const int idx = blockIdx.x * 256 + threadIdx.x;
  if (idx >= total) return;
  const uint4* p = reinterpret_cast<const uint4*>(mask) + (size_t)idx * 4;
  unsigned long long bits = 0ull;
  #pragma unroll
  for (int q = 0; q < 4; ++q) {
    uint4 v = p[q];
    unsigned wds[4] = {v.x, v.y, v.z, v.w};
    #pragma unroll
    for (int j = 0; j < 4; ++j)
      #pragma unroll
      for (int by = 0; by < 4; ++by)
        if ((wds[j] >> (by * 8)) & 0xFFu) bits |= 1ull << (q * 16 + j * 4 + by);
  }
  mbits[idx] = bits;
}

// ---------------- GEMM: 128x128, counted-vmcnt 2-stage + 8x8 supertile order ----------------
#define CQ 0.18033688011112042f   // log2(e)/8
template <int EPI>
__global__ __launch_bounds__(256, 3) void gemm2_k(const unsigned short* __restrict__ A,
                                                  const unsigned short* __restrict__ Bt,
                                                  const float* __restrict__ bias_a,
                                                  const float* __restrict__ bias_b,
                                                  const float* __restrict__ bias_c,
                                                  void* __restrict__ Cout, int N, int K) {
  __shared__ __align__(16) unsigned short As[2][128 * 64];
  __shared__ __align__(16) unsigned short Bs[2][128 * 64];
  const int t = threadIdx.x;
  const int lane = t & 63, w = t >> 6;
  const int wr = w >> 1, wc = w & 1;
  const int lr = lane & 15, lg = lane >> 4;

  const int nwg = gridDim.x;
  const int q8 = nwg >> 3;
  const int wg = (blockIdx.x & 7) * q8 + (blockIdx.x >> 3);
  const int sid = wg >> 6, within = wg & 63;
  const int smb = sid & 7, snb = sid >> 3;
  const int mb = smb * 8 + (within & 7);
  const int nb = snb * 8 + (within >> 3);
  const int m0 = mb * 128, n0 = nb * 128;

  const int srow = t >> 3;
  const unsigned cxor = (unsigned)(((t & 7) * 16) ^ (((t >> 3) & 7) << 4));
  const char* Asrc = reinterpret_cast<const char*>(A) + ((size_t)(m0 + srow) * K) * 2 + cxor;
  const char* Bsrc = reinterpret_cast<const char*>(Bt) + ((size_t)(n0 + srow) * K) * 2 + cxor;
  const size_t rstep = (size_t)32 * K * 2;
  char* AsB[2] = {reinterpret_cast<char*>(As[0]) + w * 1024, reinterpret_cast<char*>(As[1]) + w * 1024};
  char* BsB[2] = {reinterpret_cast<char*>(Bs[0]) + w * 1024, reinterpret_cast<char*>(Bs[1]) + w * 1024};

  auto stage = [&](int buf, int kt) {
    const char* ak = Asrc + (size_t)kt * 128;
    const char* bk = Bsrc + (size_t)kt * 128;
    #pragma unroll
    for (int c = 0; c < 4; ++c) {
      gload_lds16(ak + c * rstep, AsB[buf] + c * 4096);
      gload_lds16(bk + c * rstep, BsB[buf] + c * 4096);
    }
  };

  f32x4 acc[4][4] = {};
  const int nt = K >> 6;

  stage(0, 0);
  stage(1, 1);
  asm volatile("s_waitcnt vmcnt(8)" ::: "memory");
  __builtin_amdgcn_s_barrier();

  int cur = 0;
  for (int kt = 0; kt < nt; ++kt) {
    bf16x8 af[2][4], bfr[2][4];
    #pragma unroll
    for (int kk = 0; kk < 2; ++kk) {
      #pragma unroll
      for (int m = 0; m < 4; ++m)
        af[kk][m] = lds_frag(As[cur], wr * 64 + m * 16 + lr, kk * 32 + lg * 8);
      #pragma unroll
      for (int n = 0; n < 4; ++n)
        bfr[kk][n] = lds_frag(Bs[cur], wc * 64 + n * 16 + lr, kk * 32 + lg * 8);
    }
    __builtin_amdgcn_s_setprio(1);
    #pragma unroll
    for (int m = 0; m < 4; ++m)
      #pragma unroll
      for (int n = 0; n < 4; ++n)
        acc[m][n] = __builtin_amdgcn_mfma_f32_16x16x32_bf16(af[0][m], bfr[0][n], acc[m][n], 0, 0, 0);
    __builtin_amdgcn_s_setprio(0);

    asm volatile("s_waitcnt lgkmcnt(0)" ::: "memory");
    __builtin_amdgcn_s_barrier();
    if (kt + 2 < nt) {
      stage(cur, kt + 2);
      asm volatile("s_waitcnt vmcnt(8)" ::: "memory");
    } else {
      asm volatile("s_waitcnt vmcnt(0)" ::: "memory");
    }
    __builtin_amdgcn_s_barrier();

    __builtin_amdgcn_s_setprio(1);
    #pragma unroll
    for (int m = 0; m < 4; ++m)
      #pragma unroll
      for (int n = 0; n < 4; ++n)
        acc[m][n] = __builtin_amdgcn_mfma_f32_16x16x32_bf16(af[1][m], bfr[1][n], acc[m][n], 0, 0, 0);
    __builtin_amdgcn_s_setprio(0);
    cur ^= 1;
  }

  const int ccol0 = wc * 64;
  if constexpr (EPI == 3) {
    const int g3 = n0 >> 10;  // 0=Q,1=K,2=V
    const float* bias = (g3 == 0) ? bias_a : (g3 == 1) ? bias_b : bias_c;
    const float scl = (g3 == 0) ? CQ : 1.0f;
    unsigned short* Og = reinterpret_cast<unsigned short*>(Cout) + (size_t)g3 * MROWS * DMODEL;
    const int ncol0 = (n0 & 1023) + ccol0;
    float bv[4];
    #pragma unroll
    for (int n = 0; n < 4; ++n) bv[n] = bias[ncol0 + n * 16 + lr];
    #pragma unroll
    for (int m = 0; m < 4; ++m)
      #pragma unroll
      for (int n = 0; n < 4; ++n)
        #pragma unroll
        for (int i = 0; i < 4; ++i) {
          const float v = (acc[m][n][i] + bv[n]) * scl;
          const size_t row = (size_t)(m0 + wr * 64 + m * 16 + lg * 4 + i);
          Og[row * DMODEL + (ncol0 + n * 16 + lr)] = f2b(v);
        }
  } else {
    float bv[4];
    #pragma unroll
    for (int n = 0; n < 4; ++n) bv[n] = bias_a[n0 + ccol0 + n * 16 + lr];
    #pragma unroll
    for (int m = 0; m < 4; ++m)
      #pragma unroll
      for (int n = 0; n < 4; ++n)
        #pragma unroll
        for (int i = 0; i < 4; ++i) {
          float v = acc[m][n][i] + bv[n];
          if (EPI == 1) v = fmaxf(v, 0.0f);
          const size_t row = (size_t)(m0 + wr * 64 + m * 16 + lg * 4 + i);
          const size_t col = (size_t)(n0 + ccol0 + n * 16 + lr);
          reinterpret_cast<unsigned short*>(Cout)[row * N + col] = f2b(v);
        }
  }
}

// ---------------- flash attention v9 (round-14 best): low-register half-sequential ----------------
// attn4 staging; the two 32-key halves processed SEQUENTIALLY (peak live set
// st(16)+pw(8)); tree-sum denominator; launch_bounds(256,3) -> 3 waves/SIMD,
// no spills (VGPR 84). Q pre-scaled by log2(e)/8; mask fill -20.
__global__ __launch_bounds__(256, 3) void attn9_k(const unsigned short* __restrict__ Qb,
                                                  const unsigned short* __restrict__ Kb,
                                                  const unsigned short* __restrict__ Vt,
                                                  const unsigned long long* __restrict__ mbits,
                                                  unsigned short* __restrict__ ctx) {
  __shared__ __align__(16) unsigned short smem[16384];
  unsigned short* KsC = smem;
  unsigned short* KsN = smem + 4096;
  unsigned short* VsC = smem + 8192;
  unsigned short* VsN = smem + 12288;

  const int t = threadIdx.x;
  const int lane = t & 63, w = t >> 6;
  const int lo = lane & 31, hi = lane >> 5;

  const int flat = blockIdx.x;
  const int bid = (flat & 7) * 128 + (flat >> 3);   // bijective XCD swizzle (1024 wg)
  const int bh = bid >> 4, qb = bid & 15;
  const int b = bh >> 4, h = bh & 15;
  const int q0 = qb * 128 + w * 32;

  bf16x8 qf[4];
  {
    const unsigned short* qp = Qb + (size_t)(b * SS + q0 + lo) * DMODEL + h * 64 + hi * 8;
    #pragma unroll
    for (int ds = 0; ds < 4; ++ds) qf[ds] = *reinterpret_cast<const bf16x8*>(qp + ds * 16);
  }

  f32x16 ao0 = {}, ao1 = {};
  float lsum = 0.0f;

  const int srow = t >> 3;
  const int gsw = ((t & 7) - srow) & 7;
  const char* Ksrc = reinterpret_cast<const char*>(Kb) +
                     ((size_t)(b * SS + srow) * DMODEL + h * 64 + gsw * 8) * 2;
  const char* Vsrc = reinterpret_cast<const char*>(Vt) +
                     ((size_t)(bh * 64 + srow) * SS + gsw * 8) * 2;
  const unsigned wdo = (unsigned)(w * 1024);

  auto stage = [&](int kv, unsigned short* Kbuf, unsigned short* Vbuf) {
    const char* ks0 = Ksrc + (size_t)kv * (64 * DMODEL * 2);
    const char* vs0 = Vsrc + (size_t)kv * 128;
    char* kd = reinterpret_cast<char*>(Kbuf) + wdo;
    char* vd = reinterpret_cast<char*>(Vbuf) + wdo;
    gload_lds16(ks0, kd);
    gload_lds16(ks0 + (size_t)32 * DMODEL * 2, kd + 4096);
    gload_lds16(vs0, vd);
    gload_lds16(vs0 + (size_t)32 * SS * 2, vd + 4096);
  };

  const unsigned long long* mrow = mbits + (size_t)(b * SS + q0 + lo) * (SS / 64);

  stage(0, KsC, VsC);
  asm volatile("s_waitcnt vmcnt(0)" ::: "memory");
  __syncthreads();

  for (int kv = 0; kv < SS / 64; ++kv) {
    if (kv + 1 < SS / 64) stage(kv + 1, KsN, VsN);

    const unsigned long long mb = mrow[kv];
    float ls = 0.0f;

    #pragma unroll
    for (int half = 0; half < 2; ++half) {
      // QK^T for this half's 32 keys
      f32x16 st = {};
      __builtin_amdgcn_s_setprio(1);
      #pragma unroll
      for (int ds = 0; ds < 4; ++ds) {
        const int kcol = ds * 16 + hi * 8;
        st = __builtin_amdgcn_mfma_f32_32x32x16_bf16(
            frag_rot(KsC, half * 32 + lo, kcol), qf[ds], st, 0, 0, 0);
      }
      __builtin_amdgcn_s_setprio(0);

      if (__any(mb != 0ull)) {
        #pragma unroll
        for (int r = 0; r < 16; ++r) {
          const int k = (r & 3) + 8 * (r >> 2) + 4 * hi + 32 * half;
          if ((mb >> k) & 1ull) st[r] = -20.0f;
        }
      }

      // exp + tree-sum (no-max softmax; Q pre-scaled by log2(e)/8)
      #pragma unroll
      for (int r = 0; r < 16; ++r) st[r] = exp2f(st[r]);
      {
        float ps[8];
        #pragma unroll
        for (int r = 0; r < 8; ++r) ps[r] = st[r] + st[r + 8];
        #pragma unroll
        for (int r = 0; r < 4; ++r) ps[r] += ps[r + 4];
        ls += (ps[0] + ps[1]) + (ps[2] + ps[3]);
      }

      // pack half -> 8 words (T12)
      unsigned c0 = pack2bf(st[0], st[1]);
      unsigned c1 = pack2bf(st[2], st[3]);
      unsigned c2 = pack2bf(st[4], st[5]);
      unsigned c3 = pack2bf(st[6], st[7]);
      unsigned c4 = pack2bf(st[8], st[9]);
      unsigned c5 = pack2bf(st[10], st[11]);
      unsigned c6 = pack2bf(st[12], st[13]);
      unsigned c7 = pack2bf(st[14], st[15]);
      pls32(c0, c2); pls32(c1, c3); pls32(c4, c6); pls32(c5, c7);

      // PV for this half's two k-slices
      const uintx4 pv0 = {c0, c1, c2, c3};
      const uintx4 pv1 = {c4, c5, c6, c7};
      const bf16x8 pb0 = __builtin_bit_cast(bf16x8, pv0);
      const bf16x8 pb1 = __builtin_bit_cast(bf16x8, pv1);
      const int s0c = (half * 2 + 0) * 16 + hi * 8;
      const int s1c = (half * 2 + 1) * 16 + hi * 8;
      __builtin_amdgcn_s_setprio(1);
      ao0 = __builtin_amdgcn_mfma_f32_32x32x16_bf16(frag_rot(VsC, lo, s0c), pb0, ao0, 0, 0, 0);
      ao1 = __builtin_amdgcn_mfma_f32_32x32x16_bf16(frag_rot(VsC, 32 + lo, s0c), pb0, ao1, 0, 0, 0);
      ao0 = __builtin_amdgcn_mfma_f32_32x32x16_bf16(frag_rot(VsC, lo, s1c), pb1, ao0, 0, 0, 0);
      ao1 = __builtin_amdgcn_mfma_f32_32x32x16_bf16(frag_rot(VsC, 32 + lo, s1c), pb1, ao1, 0, 0, 0);
      __builtin_amdgcn_s_setprio(0);
    }

    ls += __shfl_xor(ls, 32, 64);
    lsum += ls;

    asm volatile("s_waitcnt vmcnt(0)" ::: "memory");
    __syncthreads();
    unsigned short* tk = KsC; KsC = KsN; KsN = tk;
    unsigned short* tv = VsC; VsC = VsN; VsN = tv;
  }

  const float inv = 1.0f / lsum;
  unsigned short* Ob = smem + w * 2048;
  #pragma unroll
  for (int dt = 0; dt < 2; ++dt) {
    #pragma unroll
    for (int r = 0; r < 16; ++r) {
      const int d = dt * 32 + (r & 3) + 8 * (r >> 2) + 4 * hi;
      const float v = (dt ? ao1[r] : ao0[r]) * inv;
      const unsigned off = (unsigned)((lo * 128 + d * 2) ^ ((lo & 7) << 4));
      *reinterpret_cast<unsigned short*>(reinterpret_cast<char*>(Ob) + off) = f2b(v);
    }
  }
  __syncthreads();
  const int rr = lane >> 1, xh = (lane & 1) * 64;
  char* crow_g = reinterpret_cast<char*>(ctx) +
                 ((size_t)(b * SS + q0 + rr) * DMODEL + h * 64) * 2;
  #pragma unroll
  for (int c = 0; c < 4; ++c) {
    const unsigned off = (unsigned)((rr * 128 + xh + c * 16) ^ ((rr & 7) << 4));
    const uint4 vv = *reinterpret_cast<const uint4*>(reinterpret_cast<const char*>(Ob) + off);
    *reinterpret_cast<uint4*>(crow_g + xh + c * 16) = vv;
  }
}

// ---------------- LayerNorm variants (bf16 activations, f32 math) ----------------
__global__ __launch_bounds__(256) void ln1_k(const unsigned short* __restrict__ a,
                                             const unsigned short* __restrict__ res,
                                             const float* __restrict__ g,
                                             const float* __restrict__ be,
                                             unsigned short* __restrict__ ob) {
  const int row = blockIdx.x, t = threadIdx.x;
  const ushort4 av = reinterpret_cast<const ushort4*>(a + (size_t)row * DMODEL)[t];
  const ushort4 rv = reinterpret_cast<const ushort4*>(res + (size_t)row * DMODEL)[t];
  float v0 = b2f(av.x) + b2f(rv.x), v1 = b2f(av.y) + b2f(rv.y);
  float v2 = b2f(av.z) + b2f(rv.z), v3 = b2f(av.w) + b2f(rv.w);
  float s = v0 + v1 + v2 + v3;
  float ss = v0 * v0 + v1 * v1 + v2 * v2 + v3 * v3;
  #pragma unroll
  for (int off = 1; off < 64; off <<= 1) {
    s += __shfl_xor(s, off, 64);
    ss += __shfl_xor(ss, off, 64);
  }
  __shared__ float red[8];
  const int wv = t >> 6;
  if ((t & 63) == 0) { red[wv] = s; red[4 + wv] = ss; }
  __syncthreads();
  s = red[0] + red[1] + red[2] + red[3];
  ss = red[4] + red[5] + red[6] + red[7];
  const float mu = s * (1.0f / DMODEL);
  const float rs = rsqrtf(ss * (1.0f / DMODEL) - mu * mu + 1e-6f);
  const float4 gg = reinterpret_cast<const float4*>(g)[t];
  const float4 bb = reinterpret_cast<const float4*>(be)[t];
  ushort4 u;
  u.x = f2b((v0 - mu) * rs * gg.x + bb.x);
  u.y = f2b((v1 - mu) * rs * gg.y + bb.y);
  u.z = f2b((v2 - mu) * rs * gg.z + bb.z);
  u.w = f2b((v3 - mu) * rs * gg.w + bb.w);
  reinterpret_cast<ushort4*>(ob + (size_t)row * DMODEL)[t] = u;
}

__global__ __launch_bounds__(256) void ln2_k(const unsigned short* __restrict__ a,
                                             const unsigned short* __restrict__ res,
                                             const float* __restrict__ g,
                                             const float* __restrict__ be,
                                             float* __restrict__ of) {
  const int row = blockIdx.x, t = threadIdx.x;
  const ushort4 av = reinterpret_cast<const ushort4*>(a + (size_t)row * DMODEL)[t];
  const ushort4 rv = reinterpret_cast<const ushort4*>(res + (size_t)row * DMODEL)[t];
  float v0 = b2f(av.x) + b2f(rv.x), v1 = b2f(av.y) + b2f(rv.y);
  float v2 = b2f(av.z) + b2f(rv.z), v3 = b2f(av.w) + b2f(rv.w);
  float s = v0 + v1 + v2 + v3;
  float ss = v0 * v0 + v1 * v1 + v2 * v2 + v3 * v3;
  #pragma unroll
  for (int off = 1; off < 64; off <<= 1) {
    s += __shfl_xor(s, off, 64);
    ss += __shfl_xor(ss, off, 64);
  }
  __shared__ float red[8];
  const int wv = t >> 6;
  if ((t & 63) == 0) { red[wv] = s; red[4 + wv] = ss; }
  __syncthreads();
  s = red[0] + red[1] + red[2] + red[3];
  ss = red[4] + red[5] + red[6] + red[7];
  const float mu = s * (1.0f / DMODEL);
  const float rs = rsqrtf(ss * (1.0f / DMODEL) - mu * mu + 1e-6f);
  const float4 gg = reinterpret_cast<const float4*>(g)[t];
  const float4 bb = reinterpret_cast<const float4*>(be)[t];
  float4 o;
  o.x = (v0 - mu) * rs * gg.x + bb.x;
  o.y = (v1 - mu) * rs * gg.y + bb.y;
  o.z = (v2 - mu) * rs * gg.z + bb.z;
  o.w = (v3 - mu) * rs * gg.w + bb.w;
  reinterpret_cast<float4*>(of + (size_t)row * DMODEL)[t] = o;
}

extern "C" void kernel_launch(void* const* d_in, const int* in_sizes, int n_in,
                              void* d_out, int out_size, void* d_ws, size_t ws_size,
                              hipStream_t stream) {
  const float* src = (const float*)d_in[0];
  const unsigned char* mask = (const unsigned char*)d_in[1];
  const float* Wq = (const float*)d_in[2];
  const float* bq = (const float*)d_in[3];
  const float* Wk = (const float*)d_in[4];
  const float* bk = (const float*)d_in[5];
  const float* Wv = (const float*)d_in[6];
  const float* bv = (const float*)d_in[7];
  const float* Wo = (const float*)d_in[8];
  const float* bo = (const float*)d_in[9];
  const float* ln1_g = (const float*)d_in[10];
  const float* ln1_b = (const float*)d_in[11];
  const float* W1 = (const float*)d_in[12];
  const float* b1 = (const float*)d_in[13];
  const float* W2 = (const float*)d_in[14];
  const float* b2 = (const float*)d_in[15];
  const float* ln2_g = (const float*)d_in[16];
  const float* ln2_b = (const float*)d_in[17];

  char* ws = (char*)d_ws;
  size_t off = 0;
  auto alloc = [&](size_t bytes) {
    char* p = ws + off;
    off += (bytes + 255) & ~(size_t)255;
    return p;
  };
  unsigned short* srcb = (unsigned short*)alloc((size_t)MROWS * DMODEL * 2);
  unsigned short* WqT  = (unsigned short*)alloc((size_t)DMODEL * DMODEL * 2);
  unsigned short* WkT  = (unsigned short*)alloc((size_t)DMODEL * DMODEL * 2);
  unsigned short* WvT  = (unsigned short*)alloc((size_t)DMODEL * DMODEL * 2);
  unsigned short* WoT  = (unsigned short*)alloc((size_t)DMODEL * DMODEL * 2);
  unsigned short* W1T  = (unsigned short*)alloc((size_t)FF * DMODEL * 2);
  unsigned short* W2T  = (unsigned short*)alloc((size_t)DMODEL * FF * 2);
  unsigned short* Qb   = (unsigned short*)alloc((size_t)MROWS * DMODEL * 2);
  unsigned short* Kb   = (unsigned short*)alloc((size_t)MROWS * DMODEL * 2);
  unsigned short* Vb   = (unsigned short*)alloc((size_t)MROWS * DMODEL * 2);
  unsigned short* Vt   = (unsigned short*)alloc((size_t)MROWS * DMODEL * 2);
  unsigned short* ctx  = (unsigned short*)alloc((size_t)MROWS * DMODEL * 2);
  unsigned short* aob  = (unsigned short*)alloc((size_t)MROWS * DMODEL * 2);  // Wo out (bf16)
  unsigned short* xb   = (unsigned short*)alloc((size_t)MROWS * DMODEL * 2);  // LN1 out (bf16)
  unsigned short* fob  = (unsigned short*)alloc((size_t)MROWS * DMODEL * 2);  // W2 out (bf16)
  unsigned short* hb   = (unsigned short*)alloc((size_t)MROWS * FF * 2);
  unsigned long long* mbits = (unsigned long long*)alloc((size_t)BB * SS * (SS / 64) * 8);
  float* outf = (float*)d_out;
  (void)Kb; (void)Vb;

  // converts
  f32_to_bf16_k<<<(MROWS * DMODEL / 8 + 255) / 256, 256, 0, stream>>>(src, srcb, MROWS * DMODEL / 8);
  dim3 tb(32, 8);
  transpose_convert4_k<<<dim3(32, 32, 4), tb, 0, stream>>>(Wq, Wk, Wv, Wo, WqT, WkT, WvT, WoT);
  transpose_convert_k<<<dim3(FF / 32, 32), tb, 0, stream>>>(W1, W1T, DMODEL, FF);
  transpose_convert_k<<<dim3(32, FF / 32), tb, 0, stream>>>(W2, W2T, FF, DMODEL);
  mask_pack_k<<<(BB * SS * (SS / 64) + 255) / 256, 256, 0, stream>>>(mask, mbits, BB * SS * (SS / 64));

  // fused QKV projection (N = 3072), 1536 blocks; Q pre-scaled by log2e/8
  gemm2_k<3><<<dim3(64 * 24), 256, 0, stream>>>(srcb, WqT, bq, bk, bv, Qb, 3072, DMODEL);

  v_transpose_k<<<dim3(SS / 32, 2, BB * NH), tb, 0, stream>>>(Vb, Vt);

  // low-register flash attention, 128 q/block, grid 1024
  attn9_k<<<dim3((SS / 128) * BB * NH), 256, 0, stream>>>(Qb, Kb, Vt, mbits, ctx);

  // output projection -> aob (bf16), 512 blocks
  gemm2_k<0><<<dim3(64 * 8), 256, 0, stream>>>(ctx, WoT, bo, nullptr, nullptr, aob, DMODEL, DMODEL);

  // x = LN1(srcb + att_out) -> xb (bf16)
  ln1_k<<<MROWS, 256, 0, stream>>>(aob, srcb, ln1_g, ln1_b, xb);

  // FFN: W1 (relu, 2048 blocks), W2 (512 blocks) -> fob (bf16)
  gemm2_k<1><<<dim3(64 * 32), 256, 0, stream>>>(xb, W1T, b1, nullptr, nullptr, hb, FF, DMODEL);
  gemm2_k<0><<<dim3(64 * 8), 256, 0, stream>>>(hb, W2T, b2, nullptr, nullptr, fob, DMODEL, FF);

  // out = LN2(ffn_out + x) -> d_out (f32)
  ln2_k<<<MROWS, 256, 0, stream>>>(fob, xb, ln2_g, ln2_b, outf);
}